// Round 17
// baseline (496.816 us; speedup 1.0000x reference)
//
#include <hip/hip_runtime.h>
#include <math.h>

#define ENC_K 49152
#define KSEG 64
#define KLEN (ENC_K / KSEG)   // 768

typedef __attribute__((ext_vector_type(8))) short bf16x8;
typedef __attribute__((ext_vector_type(4))) float f32x4;

__device__ inline unsigned short f2bf(float f) {
    unsigned int u = __builtin_bit_cast(unsigned int, f);
    unsigned int r = u + 0x7fffu + ((u >> 16) & 1u);
    return (unsigned short)(r >> 16);
}
__device__ inline float dot4(const float4 a, const float4 b) {
    return a.x * b.x + a.y * b.y + a.z * b.z + a.w * b.w;
}

// XCD-aware work remap (T1). Requires total % 8 == 0.
__device__ inline int xcd_work(int total) {
    int orig = blockIdx.x + gridDim.x * (blockIdx.y + gridDim.y * blockIdx.z);
    return (orig & 7) * (total >> 3) + (orig >> 3);
}

// ---------------- alpha_bar per batch ----------------
__global__ void k_alpha(const int* __restrict__ t, float* __restrict__ sab, float* __restrict__ snab) {
    int b = threadIdx.x;
    if (b < 64) {
        int tb = t[b];
        const float step = (0.02f - 1e-4f) / 999.0f;
        float ab = 1.0f;
        for (int i = 0; i <= tb; ++i) {
            float beta = 1e-4f + step * (float)i;
            ab *= (1.0f - beta);
        }
        sab[b] = sqrtf(ab);
        snab[b] = sqrtf(1.0f - ab);
    }
}

// ---------------- conv weight prep: f32 [CO][CI][3][3] -> bf16 [tap][CO][CI] ----------------
__global__ void k_prep_cw(const float* __restrict__ w, unsigned short* __restrict__ out, int CO, int CI) {
    int idx = blockIdx.x * 256 + threadIdx.x;
    int total = CO * CI * 9;
    if (idx < total) {
        int tap = idx / (CO * CI);
        int rem = idx % (CO * CI);
        int co = rem / CI, ci = rem % CI;
        out[idx] = f2bf(w[((size_t)co * CI + ci) * 9 + tap]);
    }
}

// u2 weights: f32 [3][32][3][3] -> bf16 [tap][16 co(pad)][32 ci], co>=3 zero
__global__ void k_prep_u2(const float* __restrict__ w, unsigned short* __restrict__ out) {
    int idx = blockIdx.x * 256 + threadIdx.x;
    if (idx < 9 * 16 * 32) {
        int tap = idx / 512;
        int rem = idx % 512;
        int co = rem / 32, ci = rem % 32;
        out[idx] = (co < 3) ? f2bf(w[((size_t)co * 32 + ci) * 9 + tap]) : (unsigned short)0;
    }
}

// generic f32 -> bf16 flat conversion
__global__ void k_prep_bf(const float* __restrict__ in, unsigned short* __restrict__ out, int n) {
    int i = blockIdx.x * 256 + threadIdx.x;
    if (i < n) out[i] = f2bf(in[i]);
}

// ---------------- encoder GEMM: 32x32 tile, 2x2 micro-tile per thread ----------------
__global__ void k_enc_gemm(const float* __restrict__ cond, const float* __restrict__ w,
                           float* __restrict__ partial) {
    __shared__ float As[32][68];
    __shared__ float Ws[32][68];
    int tid = threadIdx.x;
    int j = tid & 15, i = tid >> 4;
    int d0 = blockIdx.x * 32, b0 = blockIdx.y * 32;
    int k0 = blockIdx.z * KLEN;
    float a00 = 0.f, a01 = 0.f, a10 = 0.f, a11 = 0.f;
    for (int kk = 0; kk < KLEN; kk += 64) {
        for (int idx = tid; idx < 512; idx += 256) {
            int r = idx >> 4, c = (idx & 15) << 2;
            *(float4*)&As[r][c] = *(const float4*)&cond[(size_t)(b0 + r) * ENC_K + k0 + kk + c];
            *(float4*)&Ws[r][c] = *(const float4*)&w[(size_t)(d0 + r) * ENC_K + k0 + kk + c];
        }
        __syncthreads();
        const float4* aA = (const float4*)&As[i][0];
        const float4* aB = (const float4*)&As[i + 16][0];
        const float4* wA = (const float4*)&Ws[j][0];
        const float4* wB = (const float4*)&Ws[j + 16][0];
#pragma unroll
        for (int k = 0; k < 16; ++k) {
            float4 av0 = aA[k], av1 = aB[k], wv0 = wA[k], wv1 = wB[k];
            a00 += dot4(av0, wv0); a01 += dot4(av0, wv1);
            a10 += dot4(av1, wv0); a11 += dot4(av1, wv1);
        }
        __syncthreads();
    }
    size_t base = (size_t)blockIdx.z * 64;
    partial[(base + b0 + i) * 128 + d0 + j] = a00;
    partial[(base + b0 + i) * 128 + d0 + j + 16] = a01;
    partial[(base + b0 + i + 16) * 128 + d0 + j] = a10;
    partial[(base + b0 + i + 16) * 128 + d0 + j + 16] = a11;
}

__global__ void k_enc_reduce(const float* __restrict__ partial, const float* __restrict__ bias,
                             float* __restrict__ x0) {
    int idx = blockIdx.x * 256 + threadIdx.x;  // 8192 total
    float s = bias[idx & 127];
    for (int ks = 0; ks < KSEG; ++ks) s += partial[(size_t)ks * 8192 + idx];
    x0[idx] = s;
}

// ---------------- transformer ----------------
__device__ float sum128(float v, int tid, float* red) {
    if (tid < 128) red[tid] = v;
    __syncthreads();
    if (tid < 64) red[tid] += red[tid + 64]; __syncthreads();
    if (tid < 32) red[tid] += red[tid + 32]; __syncthreads();
    if (tid < 16) red[tid] += red[tid + 16]; __syncthreads();
    if (tid < 8)  red[tid] += red[tid + 8];  __syncthreads();
    if (tid < 4)  red[tid] += red[tid + 4];  __syncthreads();
    if (tid < 2)  red[tid] += red[tid + 2];  __syncthreads();
    if (tid < 1)  red[tid] += red[tid + 1];  __syncthreads();
    float s = red[0];
    __syncthreads();
    return s;
}

// attn(v,out) + ln1: one block per batch row, 512 threads
__global__ __launch_bounds__(512) void k_tf_attn(
    const float* __restrict__ xs, float* __restrict__ yo,
    const float* __restrict__ in_w, const float* __restrict__ in_b,
    const float* __restrict__ out_w, const float* __restrict__ out_b,
    const float* __restrict__ ln1_g, const float* __restrict__ ln1_b, int L) {
    __shared__ float xr[128], vr[128], tp[4][128], red[128];
    int b = blockIdx.x, tid = threadIdx.x;
    if (tid < 128) xr[tid] = xs[b * 128 + tid];
    __syncthreads();
    int d = tid & 127, s = tid >> 7;   // s in 0..3
    {
        const float4* w = (const float4*)(in_w + ((size_t)L * 384 + 256 + d) * 128) + s * 8;
        const float4* x4 = (const float4*)xr + s * 8;
        float p = 0.f;
#pragma unroll
        for (int k = 0; k < 8; ++k) p += dot4(x4[k], w[k]);
        tp[s][d] = p;
    }
    __syncthreads();
    if (tid < 128) vr[tid] = in_b[L * 384 + 256 + tid] + tp[0][tid] + tp[1][tid] + tp[2][tid] + tp[3][tid];
    __syncthreads();
    {
        const float4* w = (const float4*)(out_w + ((size_t)L * 128 + d) * 128) + s * 8;
        const float4* v4 = (const float4*)vr + s * 8;
        float p = 0.f;
#pragma unroll
        for (int k = 0; k < 8; ++k) p += dot4(v4[k], w[k]);
        tp[s][d] = p;
    }
    __syncthreads();
    float y = 0.f;
    if (tid < 128) y = xr[tid] + out_b[L * 128 + tid] + tp[0][tid] + tp[1][tid] + tp[2][tid] + tp[3][tid];
    float m1 = sum128(y, tid, red) * (1.f / 128.f);
    float c1 = y - m1;
    float v1 = sum128(c1 * c1, tid, red) * (1.f / 128.f);
    if (tid < 128)
        yo[b * 128 + tid] = c1 * rsqrtf(v1 + 1e-5f) * ln1_g[L * 128 + tid] + ln1_b[L * 128 + tid];
}

// ff1 via MFMA bf16: f1[row][j] = relu(y[row] . w1[j] + b1[j]), f1 bf16 [64][2056]
__global__ __launch_bounds__(256, 2) void k_ff1m(
    const float* __restrict__ yo, const unsigned short* __restrict__ w1b,
    const float* __restrict__ ff1_b, unsigned short* __restrict__ f1, int L) {
    __shared__ __align__(16) unsigned short xs[64 * 136];
    int tid = threadIdx.x;
    int lane = tid & 63, wv = tid >> 6, l15 = lane & 15, ch = lane >> 4;
    int n0 = blockIdx.x * 64 + wv * 16;
    for (int e = tid; e < 8192; e += 256)
        xs[(e >> 7) * 136 + (e & 127)] = f2bf(yo[e]);
    __syncthreads();
    f32x4 acc[4];
    f32x4 zf = {0.f, 0.f, 0.f, 0.f};
#pragma unroll
    for (int rg = 0; rg < 4; ++rg) acc[rg] = zf;
    const unsigned short* wrow = w1b + ((size_t)L * 2048 + n0 + l15) * 128 + ch * 8;
#pragma unroll
    for (int ks = 0; ks < 4; ++ks) {
        bf16x8 af = *(const bf16x8*)(wrow + ks * 32);
#pragma unroll
        for (int rg = 0; rg < 4; ++rg) {
            bf16x8 bv = *(const bf16x8*)(xs + (rg * 16 + l15) * 136 + ks * 32 + ch * 8);
            acc[rg] = __builtin_amdgcn_mfma_f32_16x16x32_bf16(af, bv, acc[rg], 0, 0, 0);
        }
    }
#pragma unroll
    for (int rg = 0; rg < 4; ++rg) {
        ushort4 o;
#pragma unroll
        for (int r = 0; r < 4; ++r)
            ((unsigned short*)&o)[r] =
                f2bf(fmaxf(acc[rg][r] + ff1_b[L * 2048 + n0 + ch * 4 + r], 0.f));
        *(ushort4*)(f1 + (size_t)(rg * 16 + l15) * 2056 + n0 + ch * 4) = o;
    }
}

// ff2 via MFMA bf16, K split 4x512: part[(ks*64+row)*128+d]
__global__ __launch_bounds__(256, 2) void k_ff2m(
    const unsigned short* __restrict__ f1, const unsigned short* __restrict__ w2b,
    float* __restrict__ part, int L) {
    int tid = threadIdx.x;
    int lane = tid & 63, wv = tid >> 6, l15 = lane & 15, ch = lane >> 4;
    int ks = blockIdx.x;               // 0..3 -> K slice 512
    int dw = blockIdx.y * 64 + wv * 16;
    f32x4 acc[4];
    f32x4 zf = {0.f, 0.f, 0.f, 0.f};
#pragma unroll
    for (int rg = 0; rg < 4; ++rg) acc[rg] = zf;
    const unsigned short* wrow = w2b + ((size_t)L * 128 + dw + l15) * 2048 + ks * 512 + ch * 8;
    const unsigned short* frow = f1 + ks * 512 + ch * 8;
#pragma unroll
    for (int kst = 0; kst < 16; ++kst) {
        bf16x8 af = *(const bf16x8*)(wrow + kst * 32);
#pragma unroll
        for (int rg = 0; rg < 4; ++rg) {
            bf16x8 bv = *(const bf16x8*)(frow + (size_t)(rg * 16 + l15) * 2056 + kst * 32);
            acc[rg] = __builtin_amdgcn_mfma_f32_16x16x32_bf16(af, bv, acc[rg], 0, 0, 0);
        }
    }
#pragma unroll
    for (int rg = 0; rg < 4; ++rg)
        *(float4*)&part[((size_t)ks * 64 + rg * 16 + l15) * 128 + dw + ch * 4] = *(float4*)&acc[rg];
}

// reduce partials + residual + ln2 -> xs; grid 64, 128 thr
__global__ __launch_bounds__(128) void k_tf_red(
    const float* __restrict__ part, const float* __restrict__ yo,
    float* __restrict__ xs, const float* __restrict__ ff2_b,
    const float* __restrict__ ln2_g, const float* __restrict__ ln2_b, int L) {
    __shared__ float red[128];
    int b = blockIdx.x, tid = threadIdx.x;
    float y2 = yo[b * 128 + tid] + ff2_b[L * 128 + tid];
#pragma unroll
    for (int ks = 0; ks < 4; ++ks) y2 += part[((size_t)ks * 64 + b) * 128 + tid];
    float m2 = sum128(y2, tid, red) * (1.f / 128.f);
    float c2 = y2 - m2;
    float v2 = sum128(c2 * c2, tid, red) * (1.f / 128.f);
    xs[b * 128 + tid] = c2 * rsqrtf(v2 + 1e-5f) * ln2_g[L * 128 + tid] + ln2_b[L * 128 + tid];
}

// ---------------- mid projection ----------------
__global__ void k_mid(const float* __restrict__ xe, const float* __restrict__ mid_w,
                      const float* __restrict__ mid_b, float* __restrict__ mid) {
    int b = blockIdx.x, c = threadIdx.x;  // 64 threads
    float s = mid_b[c];
    const float* xr = xe + b * 128;
    const float* wr = mid_w + c * 128;
    for (int k = 0; k < 128; ++k) s += xr[k] * wr[k];
    mid[b * 64 + c] = s;
}

// ---------------- conv1: 3->32 direct f32 (r13 form), tile 32x16, COT=16, PX=2 ----------------
__global__ __launch_bounds__(256, 4) void k_conv1(
    const float* __restrict__ tgt, const float* __restrict__ noise,
    const float* __restrict__ sab, const float* __restrict__ snab,
    const float* __restrict__ wgt, const float* __restrict__ bias,
    unsigned short* __restrict__ h1, int b0) {
    __shared__ float it[3][18][35];
    __shared__ float wt[16][3][9];
    int tid = threadIdx.x;
    int tx = tid & 15, ty = tid >> 4;      // tx: 2-px group, ty: row 0..15
    int total = gridDim.x * gridDim.y * gridDim.z;
    int w = xcd_work(total);
    int bx = w % gridDim.x; int t2 = w / gridDim.x;
    int by = t2 % gridDim.y; int bz = t2 / gridDim.y;
    int bl = bz >> 1, g = bz & 1;
    int bg = b0 + bl, co0 = g * 16;
    float za = sab[bg], zb = snab[bg];
    for (int idx = tid; idx < 3 * 18 * 34; idx += 256) {
        int c = idx / (18 * 34), rem = idx % (18 * 34);
        int yy = rem / 34, xx = rem % 34;
        int gy = by * 16 + yy - 1, gx = bx * 32 + xx - 1;
        float v = 0.f;
        if (gy >= 0 && gy < 128 && gx >= 0 && gx < 128) {
            size_t off = (((size_t)bg * 3 + c) * 128 + gy) * 128 + gx;
            v = za * tgt[off] + zb * noise[off];
        }
        it[c][yy][xx] = v;
    }
    for (int idx = tid; idx < 16 * 27; idx += 256) {
        int co = idx / 27, rem = idx % 27;
        wt[co][rem / 9][rem % 9] = wgt[(size_t)(co0 + co) * 27 + rem];
    }
    __syncthreads();
    float acc[16][2];
#pragma unroll
    for (int co = 0; co < 16; ++co) { acc[co][0] = 0.f; acc[co][1] = 0.f; }
#pragma unroll
    for (int c = 0; c < 3; ++c)
#pragma unroll
        for (int ky = 0; ky < 3; ++ky) {
            float win[4];
#pragma unroll
            for (int i = 0; i < 4; ++i) win[i] = it[c][ty + ky][tx * 2 + i];
#pragma unroll
            for (int kx = 0; kx < 3; ++kx)
#pragma unroll
                for (int co = 0; co < 16; ++co) {
                    float ww = wt[co][c][ky * 3 + kx];
                    acc[co][0] += win[kx] * ww;
                    acc[co][1] += win[kx + 1] * ww;
                }
        }
    int gy = by * 16 + ty, gx0 = bx * 32 + tx * 2;
#pragma unroll
    for (int p = 0; p < 2; ++p) {
        __attribute__((aligned(16))) unsigned short ov[16];
#pragma unroll
        for (int co = 0; co < 16; ++co)
            ov[co] = f2bf(fmaxf(acc[co][p] + bias[co0 + co], 0.f));
        size_t o = (((size_t)bl * 128 + gy) * 128 + gx0 + p) * 32 + co0;
        *(float4*)(h1 + o) = *(float4*)&ov[0];
        *(float4*)(h1 + o + 8) = *(float4*)&ov[8];
    }
}

// ---------------- MFMA 3x3 conv: bf16 NHWC in/out, f32 accum (round-10 proven) ----------------
template <int CIN, int COB, int COUT, int MOUT>
__global__ __launch_bounds__(256, 2) void k_convMg(
    const unsigned short* __restrict__ in, const unsigned short* __restrict__ wb,
    const float* __restrict__ bias, const float* __restrict__ mid,
    unsigned short* __restrict__ out, int b0) {
    const int GROUPS = COUT / (16 * COB);
    __shared__ __align__(16) unsigned short in_t[10 * 34 * 40];
    __shared__ __align__(16) unsigned short w_t[9 * COB * 16 * 40];
    int tid = threadIdx.x;
    int total = gridDim.x * gridDim.y * gridDim.z;
    int wk = xcd_work(total);
    int bx = wk % gridDim.x; int t2 = wk / gridDim.x;
    int by = t2 % gridDim.y; int bz = t2 / gridDim.y;
    int bl = bz / GROUPS, g = bz % GROUPS;
    int bg = b0 + bl;
    int co0 = g * COB * 16;
    int lane = tid & 63, wv = tid >> 6;
    int l15 = lane & 15, ch = lane >> 4;

    f32x4 acc[2][2][COB];
    f32x4 zf = {0.f, 0.f, 0.f, 0.f};
#pragma unroll
    for (int a = 0; a < 2; ++a)
#pragma unroll
        for (int bq = 0; bq < 2; ++bq)
#pragma unroll
            for (int c = 0; c < COB; ++c) acc[a][bq][c] = zf;

    for (int cs = 0; cs < CIN / 32; ++cs) {
        if (cs) __syncthreads();
        for (int c = tid; c < 10 * 34 * 4; c += 256) {
            int cc = c & 3, pix = c >> 2;
            int xx = pix % 34, yy = pix / 34;
            int gy = by * 8 + yy - 1, gx = bx * 32 + xx - 1;
            bf16x8 v = {0, 0, 0, 0, 0, 0, 0, 0};
            if (gy >= 0 && gy < 128 && gx >= 0 && gx < 128)
                v = *(const bf16x8*)(in + (((size_t)bl * 128 + gy) * 128 + gx) * CIN + cs * 32 + cc * 8);
            *(bf16x8*)(in_t + pix * 40 + cc * 8) = v;
        }
        for (int c = tid; c < 9 * COB * 16 * 4; c += 256) {
            int cc = c & 3, row = c >> 2;
            int tap = row / (COB * 16), co = row % (COB * 16);
            bf16x8 v = *(const bf16x8*)(wb + ((size_t)(tap * COUT + co0 + co)) * CIN + cs * 32 + cc * 8);
            *(bf16x8*)(w_t + row * 40 + cc * 8) = v;
        }
        __syncthreads();
#pragma unroll
        for (int ky = 0; ky < 3; ++ky)
#pragma unroll
            for (int kx = 0; kx < 3; ++kx) {
                int tap = ky * 3 + kx;
                bf16x8 af[COB];
#pragma unroll
                for (int cb = 0; cb < COB; ++cb)
                    af[cb] = *(const bf16x8*)(w_t + (tap * COB * 16 + cb * 16 + l15) * 40 + ch * 8);
#pragma unroll
                for (int yl = 0; yl < 2; ++yl) {
                    int yloc = 2 * wv + yl + ky;
#pragma unroll
                    for (int xt = 0; xt < 2; ++xt) {
                        int xloc = xt * 16 + l15 + kx;
                        bf16x8 bfv = *(const bf16x8*)(in_t + (yloc * 34 + xloc) * 40 + ch * 8);
#pragma unroll
                        for (int cb = 0; cb < COB; ++cb)
                            acc[yl][xt][cb] = __builtin_amdgcn_mfma_f32_16x16x32_bf16(
                                af[cb], bfv, acc[yl][xt][cb], 0, 0, 0);
                    }
                }
            }
    }
#pragma unroll
    for (int yl = 0; yl < 2; ++yl) {
        int gy = by * 8 + 2 * wv + yl;
#pragma unroll
        for (int xt = 0; xt < 2; ++xt) {
            int gx = bx * 32 + xt * 16 + l15;
            size_t pixo = (((size_t)bl * 128 + gy) * 128 + gx) * COUT;
#pragma unroll
            for (int cb = 0; cb < COB; ++cb) {
                int co = co0 + cb * 16 + ch * 4;
                ushort4 o;
#pragma unroll
                for (int r = 0; r < 4; ++r) {
                    float v = acc[yl][xt][cb][r] + bias[co + r];
                    v = fmaxf(v, 0.f);
                    if (MOUT == 2) v += mid[bg * 64 + co + r];
                    ((unsigned short*)&o)[r] = f2bf(v);
                }
                *(ushort4*)(out + pixo + co) = o;
            }
        }
    }
}

// ---------------- u2 via MFMA (co 0..2 of 16-pad) + fused MSE ----------------
__global__ __launch_bounds__(256, 3) void k_u2m(
    const unsigned short* __restrict__ h3, const unsigned short* __restrict__ wbu2,
    const float* __restrict__ u2_b, const float* __restrict__ noise,
    float* __restrict__ partial, int b0) {
    __shared__ __align__(16) unsigned short in_t[340 * 40];
    __shared__ __align__(16) unsigned short w_t[9 * 16 * 40];
    __shared__ float rs[256];
    int tid = threadIdx.x;
    int total = gridDim.x * gridDim.y * gridDim.z;
    int wk = xcd_work(total);
    int bx = wk % gridDim.x; int t2 = wk / gridDim.x;
    int by = t2 % gridDim.y; int bl = t2 / gridDim.y;
    int bg = b0 + bl;
    int lane = tid & 63, wv = tid >> 6, l15 = lane & 15, ch = lane >> 4;

    for (int c = tid; c < 340 * 4; c += 256) {
        int cc = c & 3, pix = c >> 2;
        int xx = pix % 34, yy = pix / 34;
        int gy = by * 8 + yy - 1, gx = bx * 32 + xx - 1;
        bf16x8 v = {0, 0, 0, 0, 0, 0, 0, 0};
        if (gy >= 0 && gy < 128 && gx >= 0 && gx < 128)
            v = *(const bf16x8*)(h3 + (((size_t)bl * 128 + gy) * 128 + gx) * 32 + cc * 8);
        *(bf16x8*)(in_t + pix * 40 + cc * 8) = v;
    }
    for (int c = tid; c < 9 * 16 * 4; c += 256) {
        int cc = c & 3, row = c >> 2;
        bf16x8 v = *(const bf16x8*)(wbu2 + (size_t)row * 32 + cc * 8);
        *(bf16x8*)(w_t + row * 40 + cc * 8) = v;
    }
    __syncthreads();

    f32x4 acc[2][2];
    f32x4 zf = {0.f, 0.f, 0.f, 0.f};
    acc[0][0] = zf; acc[0][1] = zf; acc[1][0] = zf; acc[1][1] = zf;
#pragma unroll
    for (int ky = 0; ky < 3; ++ky)
#pragma unroll
        for (int kx = 0; kx < 3; ++kx) {
            int tap = ky * 3 + kx;
            bf16x8 af = *(const bf16x8*)(w_t + (tap * 16 + l15) * 40 + ch * 8);
#pragma unroll
            for (int yl = 0; yl < 2; ++yl) {
                int yloc = 2 * wv + yl + ky;
#pragma unroll
                for (int xt = 0; xt < 2; ++xt) {
                    int xloc = xt * 16 + l15 + kx;
                    bf16x8 bfv = *(const bf16x8*)(in_t + (yloc * 34 + xloc) * 40 + ch * 8);
                    acc[yl][xt] = __builtin_amdgcn_mfma_f32_16x16x32_bf16(af, bfv, acc[yl][xt], 0, 0, 0);
                }
            }
        }
    float ss = 0.f;
    if (ch == 0) {
#pragma unroll
        for (int yl = 0; yl < 2; ++yl) {
            int gy = by * 8 + 2 * wv + yl;
#pragma unroll
            for (int xt = 0; xt < 2; ++xt) {
                int gx = bx * 32 + xt * 16 + l15;
#pragma unroll
                for (int r = 0; r < 3; ++r) {
                    float v = acc[yl][xt][r] + u2_b[r];
                    float d = v - noise[(((size_t)bg * 3 + r) * 128 + gy) * 128 + gx];
                    ss += d * d;
                }
            }
        }
    }
    rs[tid] = ss;
    __syncthreads();
    for (int s = 128; s > 0; s >>= 1) {
        if (tid < s) rs[tid] += rs[tid + s];
        __syncthreads();
    }
    if (tid == 0) partial[bg * 64 + by * 4 + bx] = rs[0];
}

// ---------------- final MSE reduction ----------------
__global__ void k_final(const float* __restrict__ partial, float* __restrict__ out) {
    __shared__ float rs[256];
    int tid = threadIdx.x;
    float s = 0.f;
    for (int i = tid; i < 4096; i += 256) s += partial[i];
    rs[tid] = s;
    __syncthreads();
    for (int st = 128; st > 0; st >>= 1) {
        if (tid < st) rs[tid] += rs[tid + st];
        __syncthreads();
    }
    if (tid == 0) out[0] = rs[0] / 3145728.0f;
}

extern "C" void kernel_launch(void* const* d_in, const int* in_sizes, int n_in,
                              void* d_out, int out_size, void* d_ws, size_t ws_size,
                              hipStream_t stream) {
    const float* cond   = (const float*)d_in[0];
    const float* tgt    = (const float*)d_in[1];
    const float* noise  = (const float*)d_in[2];
    const int*   t      = (const int*)d_in[3];
    const float* enc_w  = (const float*)d_in[4];
    const float* enc_b  = (const float*)d_in[5];
    const float* in_w   = (const float*)d_in[6];
    const float* in_b   = (const float*)d_in[7];
    const float* out_w  = (const float*)d_in[8];
    const float* out_b  = (const float*)d_in[9];
    const float* ff1_w  = (const float*)d_in[10];
    const float* ff1_b  = (const float*)d_in[11];
    const float* ff2_w  = (const float*)d_in[12];
    const float* ff2_b  = (const float*)d_in[13];
    const float* ln1_g  = (const float*)d_in[14];
    const float* ln1_b  = (const float*)d_in[15];
    const float* ln2_g  = (const float*)d_in[16];
    const float* ln2_b  = (const float*)d_in[17];
    const float* d1_w   = (const float*)d_in[18];
    const float* d1_b   = (const float*)d_in[19];
    const float* d2_w   = (const float*)d_in[20];
    const float* d2_b   = (const float*)d_in[21];
    const float* mid_w  = (const float*)d_in[22];
    const float* mid_b  = (const float*)d_in[23];
    const float* u1_w   = (const float*)d_in[24];
    const float* u1_b   = (const float*)d_in[25];
    const float* u2_w   = (const float*)d_in[26];
    const float* u2_b   = (const float*)d_in[27];

    float* ws = (float*)d_ws;
    // control region: 131072 floats
    float* sab     = ws;                    // 64
    float* snab    = ws + 64;               // 64
    float* x0      = ws + 128;              // 8192
    float* mid     = ws + 16512;            // 4096
    float* msepart = ws + 86144;            // 4096
    unsigned short* wb2  = (unsigned short*)(ws + 90240);   // 18432 bf16
    unsigned short* wbu1 = (unsigned short*)(ws + 99456);   // 18432 bf16
    unsigned short* wbu2 = (unsigned short*)(ws + 108672);  // 4608 bf16

    const size_t SMALL = 131072;
    const size_t ENCP = (size_t)KSEG * 8192;                // 524288
    float* encpart = ws + SMALL;
    float* tfy     = encpart + ENCP;                        // 8192
    unsigned short* tff1 = (unsigned short*)(tfy + 8192);   // 64*2056 bf16 = 65792 f32
    float* tfpart  = tfy + 8192 + 65792;                    // 4*64*128 = 32768
    unsigned short* wbf1 = (unsigned short*)(tfpart + 32768);          // 524288 bf16
    unsigned short* wbf2 = (unsigned short*)(tfpart + 32768 + 262144); // 524288 bf16

    size_t fixed = SMALL + ENCP + 8192 + 65792 + 32768 + 262144 + 262144;
    size_t avail = (ws_size / 4 > fixed) ? (ws_size / 4 - fixed) : 0;
    // per image: h1(32ch) + h2(64ch) + h3(32ch) bf16 = 1048576 f32-slots
    // NB capped at 8: per-chunk working set ~33.6 MB ~= aggregate L2 (32 MB)
    // so producer writes are overwritten in-cache by the next chunk (writeback elim).
    int NB = 1;
    const int cands[4] = {8, 4, 2, 1};
    for (int ci = 0; ci < 4; ++ci) {
        if ((size_t)cands[ci] * 1048576ull <= avail) { NB = cands[ci]; break; }
    }
    unsigned short* hb1 = (unsigned short*)(ws + fixed);
    unsigned short* hb2 = (unsigned short*)(ws + fixed + (size_t)NB * 262144ull);
    unsigned short* hb3 = (unsigned short*)(ws + fixed + (size_t)NB * 786432ull);

    k_alpha<<<1, 64, 0, stream>>>(t, sab, snab);
    k_prep_cw<<<72, 256, 0, stream>>>(d2_w, wb2, 64, 32);
    k_prep_cw<<<72, 256, 0, stream>>>(u1_w, wbu1, 32, 64);
    k_prep_u2<<<18, 256, 0, stream>>>(u2_w, wbu2);
    k_prep_bf<<<2048, 256, 0, stream>>>(ff1_w, wbf1, 524288);
    k_prep_bf<<<2048, 256, 0, stream>>>(ff2_w, wbf2, 524288);
    k_enc_gemm<<<dim3(4, 2, KSEG), 256, 0, stream>>>(cond, enc_w, encpart);
    k_enc_reduce<<<32, 256, 0, stream>>>(encpart, enc_b, x0);
    for (int L = 0; L < 2; ++L) {
        k_tf_attn<<<64, 512, 0, stream>>>(x0, tfy, in_w, in_b, out_w, out_b, ln1_g, ln1_b, L);
        k_ff1m<<<32, 256, 0, stream>>>(tfy, wbf1, ff1_b, tff1, L);
        k_ff2m<<<dim3(4, 2), 256, 0, stream>>>(tff1, wbf2, tfpart, L);
        k_tf_red<<<64, 128, 0, stream>>>(tfpart, tfy, x0, ff2_b, ln2_g, ln2_b, L);
    }
    k_mid<<<64, 64, 0, stream>>>(x0, mid_w, mid_b, mid);

    for (int cb = 0; cb < 64; cb += NB) {
        // conv1: 3->32 direct f32, q_sample fused, 32x16 tiles, 2 groups (r13 form)
        k_conv1<<<dim3(4, 8, NB * 2), 256, 0, stream>>>(
            tgt, noise, sab, snab, d1_w, d1_b, hb1, cb);
        // conv2: 32->64 MFMA, all 64 co per block, relu + mid
        k_convMg<32, 4, 64, 2><<<dim3(4, 16, NB), 256, 0, stream>>>(
            hb1, wb2, d2_b, mid, hb2, cb);
        // u1: 64->32 MFMA, relu
        k_convMg<64, 2, 32, 1><<<dim3(4, 16, NB), 256, 0, stream>>>(
            hb2, wbu1, u1_b, nullptr, hb3, cb);
        // u2: 32->3 MFMA + fused MSE
        k_u2m<<<dim3(4, 16, NB), 256, 0, stream>>>(
            hb3, wbu2, u2_b, noise, msepart, cb);
    }

    k_final<<<1, 256, 0, stream>>>(msepart, (float*)d_out);
}

// Round 18
// 387.993 us; speedup vs baseline: 1.2805x; 1.2805x over previous
//
#include <hip/hip_runtime.h>
#include <math.h>

#define ENC_K 49152
#define KSEG 64
#define KLEN (ENC_K / KSEG)   // 768

typedef __attribute__((ext_vector_type(8))) short bf16x8;
typedef __attribute__((ext_vector_type(4))) float f32x4;

__device__ inline unsigned short f2bf(float f) {
    unsigned int u = __builtin_bit_cast(unsigned int, f);
    unsigned int r = u + 0x7fffu + ((u >> 16) & 1u);
    return (unsigned short)(r >> 16);
}
__device__ inline float dot4(const float4 a, const float4 b) {
    return a.x * b.x + a.y * b.y + a.z * b.z + a.w * b.w;
}

// XCD-aware work remap (T1). Requires total % 8 == 0.
__device__ inline int xcd_work(int total) {
    int orig = blockIdx.x + gridDim.x * (blockIdx.y + gridDim.y * blockIdx.z);
    return (orig & 7) * (total >> 3) + (orig >> 3);
}

// ---------------- alpha_bar per batch ----------------
__global__ void k_alpha(const int* __restrict__ t, float* __restrict__ sab, float* __restrict__ snab) {
    int b = threadIdx.x;
    if (b < 64) {
        int tb = t[b];
        const float step = (0.02f - 1e-4f) / 999.0f;
        float ab = 1.0f;
        for (int i = 0; i <= tb; ++i) {
            float beta = 1e-4f + step * (float)i;
            ab *= (1.0f - beta);
        }
        sab[b] = sqrtf(ab);
        snab[b] = sqrtf(1.0f - ab);
    }
}

// ---------------- conv weight prep: f32 [CO][CI][3][3] -> bf16 [tap][CO][CI] ----------------
__global__ void k_prep_cw(const float* __restrict__ w, unsigned short* __restrict__ out, int CO, int CI) {
    int idx = blockIdx.x * 256 + threadIdx.x;
    int total = CO * CI * 9;
    if (idx < total) {
        int tap = idx / (CO * CI);
        int rem = idx % (CO * CI);
        int co = rem / CI, ci = rem % CI;
        out[idx] = f2bf(w[((size_t)co * CI + ci) * 9 + tap]);
    }
}

// u2 weights: f32 [3][32][3][3] -> bf16 [tap][16 co(pad)][32 ci], co>=3 zero
__global__ void k_prep_u2(const float* __restrict__ w, unsigned short* __restrict__ out) {
    int idx = blockIdx.x * 256 + threadIdx.x;
    if (idx < 9 * 16 * 32) {
        int tap = idx / 512;
        int rem = idx % 512;
        int co = rem / 32, ci = rem % 32;
        out[idx] = (co < 3) ? f2bf(w[((size_t)co * 32 + ci) * 9 + tap]) : (unsigned short)0;
    }
}

// generic f32 -> bf16 flat conversion
__global__ void k_prep_bf(const float* __restrict__ in, unsigned short* __restrict__ out, int n) {
    int i = blockIdx.x * 256 + threadIdx.x;
    if (i < n) out[i] = f2bf(in[i]);
}

// ---------------- encoder GEMM: 32x32 tile, 2x2 micro-tile per thread ----------------
__global__ void k_enc_gemm(const float* __restrict__ cond, const float* __restrict__ w,
                           float* __restrict__ partial) {
    __shared__ float As[32][68];
    __shared__ float Ws[32][68];
    int tid = threadIdx.x;
    int j = tid & 15, i = tid >> 4;
    int d0 = blockIdx.x * 32, b0 = blockIdx.y * 32;
    int k0 = blockIdx.z * KLEN;
    float a00 = 0.f, a01 = 0.f, a10 = 0.f, a11 = 0.f;
    for (int kk = 0; kk < KLEN; kk += 64) {
        for (int idx = tid; idx < 512; idx += 256) {
            int r = idx >> 4, c = (idx & 15) << 2;
            *(float4*)&As[r][c] = *(const float4*)&cond[(size_t)(b0 + r) * ENC_K + k0 + kk + c];
            *(float4*)&Ws[r][c] = *(const float4*)&w[(size_t)(d0 + r) * ENC_K + k0 + kk + c];
        }
        __syncthreads();
        const float4* aA = (const float4*)&As[i][0];
        const float4* aB = (const float4*)&As[i + 16][0];
        const float4* wA = (const float4*)&Ws[j][0];
        const float4* wB = (const float4*)&Ws[j + 16][0];
#pragma unroll
        for (int k = 0; k < 16; ++k) {
            float4 av0 = aA[k], av1 = aB[k], wv0 = wA[k], wv1 = wB[k];
            a00 += dot4(av0, wv0); a01 += dot4(av0, wv1);
            a10 += dot4(av1, wv0); a11 += dot4(av1, wv1);
        }
        __syncthreads();
    }
    size_t base = (size_t)blockIdx.z * 64;
    partial[(base + b0 + i) * 128 + d0 + j] = a00;
    partial[(base + b0 + i) * 128 + d0 + j + 16] = a01;
    partial[(base + b0 + i + 16) * 128 + d0 + j] = a10;
    partial[(base + b0 + i + 16) * 128 + d0 + j + 16] = a11;
}

__global__ void k_enc_reduce(const float* __restrict__ partial, const float* __restrict__ bias,
                             float* __restrict__ x0) {
    int idx = blockIdx.x * 256 + threadIdx.x;  // 8192 total
    float s = bias[idx & 127];
    for (int ks = 0; ks < KSEG; ++ks) s += partial[(size_t)ks * 8192 + idx];
    x0[idx] = s;
}

// ---------------- transformer ----------------
__device__ float sum128(float v, int tid, float* red) {
    if (tid < 128) red[tid] = v;
    __syncthreads();
    if (tid < 64) red[tid] += red[tid + 64]; __syncthreads();
    if (tid < 32) red[tid] += red[tid + 32]; __syncthreads();
    if (tid < 16) red[tid] += red[tid + 16]; __syncthreads();
    if (tid < 8)  red[tid] += red[tid + 8];  __syncthreads();
    if (tid < 4)  red[tid] += red[tid + 4];  __syncthreads();
    if (tid < 2)  red[tid] += red[tid + 2];  __syncthreads();
    if (tid < 1)  red[tid] += red[tid + 1];  __syncthreads();
    float s = red[0];
    __syncthreads();
    return s;
}

// attn(v,out) + ln1: one block per batch row, 512 threads
__global__ __launch_bounds__(512) void k_tf_attn(
    const float* __restrict__ xs, float* __restrict__ yo,
    const float* __restrict__ in_w, const float* __restrict__ in_b,
    const float* __restrict__ out_w, const float* __restrict__ out_b,
    const float* __restrict__ ln1_g, const float* __restrict__ ln1_b, int L) {
    __shared__ float xr[128], vr[128], tp[4][128], red[128];
    int b = blockIdx.x, tid = threadIdx.x;
    if (tid < 128) xr[tid] = xs[b * 128 + tid];
    __syncthreads();
    int d = tid & 127, s = tid >> 7;   // s in 0..3
    {
        const float4* w = (const float4*)(in_w + ((size_t)L * 384 + 256 + d) * 128) + s * 8;
        const float4* x4 = (const float4*)xr + s * 8;
        float p = 0.f;
#pragma unroll
        for (int k = 0; k < 8; ++k) p += dot4(x4[k], w[k]);
        tp[s][d] = p;
    }
    __syncthreads();
    if (tid < 128) vr[tid] = in_b[L * 384 + 256 + tid] + tp[0][tid] + tp[1][tid] + tp[2][tid] + tp[3][tid];
    __syncthreads();
    {
        const float4* w = (const float4*)(out_w + ((size_t)L * 128 + d) * 128) + s * 8;
        const float4* v4 = (const float4*)vr + s * 8;
        float p = 0.f;
#pragma unroll
        for (int k = 0; k < 8; ++k) p += dot4(v4[k], w[k]);
        tp[s][d] = p;
    }
    __syncthreads();
    float y = 0.f;
    if (tid < 128) y = xr[tid] + out_b[L * 128 + tid] + tp[0][tid] + tp[1][tid] + tp[2][tid] + tp[3][tid];
    float m1 = sum128(y, tid, red) * (1.f / 128.f);
    float c1 = y - m1;
    float v1 = sum128(c1 * c1, tid, red) * (1.f / 128.f);
    if (tid < 128)
        yo[b * 128 + tid] = c1 * rsqrtf(v1 + 1e-5f) * ln1_g[L * 128 + tid] + ln1_b[L * 128 + tid];
}

// ff1 via MFMA bf16: f1[row][j] = relu(y[row] . w1[j] + b1[j]), f1 bf16 [64][2056]
__global__ __launch_bounds__(256, 2) void k_ff1m(
    const float* __restrict__ yo, const unsigned short* __restrict__ w1b,
    const float* __restrict__ ff1_b, unsigned short* __restrict__ f1, int L) {
    __shared__ __align__(16) unsigned short xs[64 * 136];
    int tid = threadIdx.x;
    int lane = tid & 63, wv = tid >> 6, l15 = lane & 15, ch = lane >> 4;
    int n0 = blockIdx.x * 64 + wv * 16;
    for (int e = tid; e < 8192; e += 256)
        xs[(e >> 7) * 136 + (e & 127)] = f2bf(yo[e]);
    __syncthreads();
    f32x4 acc[4];
    f32x4 zf = {0.f, 0.f, 0.f, 0.f};
#pragma unroll
    for (int rg = 0; rg < 4; ++rg) acc[rg] = zf;
    const unsigned short* wrow = w1b + ((size_t)L * 2048 + n0 + l15) * 128 + ch * 8;
#pragma unroll
    for (int ks = 0; ks < 4; ++ks) {
        bf16x8 af = *(const bf16x8*)(wrow + ks * 32);
#pragma unroll
        for (int rg = 0; rg < 4; ++rg) {
            bf16x8 bv = *(const bf16x8*)(xs + (rg * 16 + l15) * 136 + ks * 32 + ch * 8);
            acc[rg] = __builtin_amdgcn_mfma_f32_16x16x32_bf16(af, bv, acc[rg], 0, 0, 0);
        }
    }
#pragma unroll
    for (int rg = 0; rg < 4; ++rg) {
        ushort4 o;
#pragma unroll
        for (int r = 0; r < 4; ++r)
            ((unsigned short*)&o)[r] =
                f2bf(fmaxf(acc[rg][r] + ff1_b[L * 2048 + n0 + ch * 4 + r], 0.f));
        *(ushort4*)(f1 + (size_t)(rg * 16 + l15) * 2056 + n0 + ch * 4) = o;
    }
}

// ff2 via MFMA bf16, K split 4x512: part[(ks*64+row)*128+d]
__global__ __launch_bounds__(256, 2) void k_ff2m(
    const unsigned short* __restrict__ f1, const unsigned short* __restrict__ w2b,
    float* __restrict__ part, int L) {
    int tid = threadIdx.x;
    int lane = tid & 63, wv = tid >> 6, l15 = lane & 15, ch = lane >> 4;
    int ks = blockIdx.x;               // 0..3 -> K slice 512
    int dw = blockIdx.y * 64 + wv * 16;
    f32x4 acc[4];
    f32x4 zf = {0.f, 0.f, 0.f, 0.f};
#pragma unroll
    for (int rg = 0; rg < 4; ++rg) acc[rg] = zf;
    const unsigned short* wrow = w2b + ((size_t)L * 128 + dw + l15) * 2048 + ks * 512 + ch * 8;
    const unsigned short* frow = f1 + ks * 512 + ch * 8;
#pragma unroll
    for (int kst = 0; kst < 16; ++kst) {
        bf16x8 af = *(const bf16x8*)(wrow + kst * 32);
#pragma unroll
        for (int rg = 0; rg < 4; ++rg) {
            bf16x8 bv = *(const bf16x8*)(frow + (size_t)(rg * 16 + l15) * 2056 + kst * 32);
            acc[rg] = __builtin_amdgcn_mfma_f32_16x16x32_bf16(af, bv, acc[rg], 0, 0, 0);
        }
    }
#pragma unroll
    for (int rg = 0; rg < 4; ++rg)
        *(float4*)&part[((size_t)ks * 64 + rg * 16 + l15) * 128 + dw + ch * 4] = *(float4*)&acc[rg];
}

// reduce partials + residual + ln2 -> xs; grid 64, 128 thr
__global__ __launch_bounds__(128) void k_tf_red(
    const float* __restrict__ part, const float* __restrict__ yo,
    float* __restrict__ xs, const float* __restrict__ ff2_b,
    const float* __restrict__ ln2_g, const float* __restrict__ ln2_b, int L) {
    __shared__ float red[128];
    int b = blockIdx.x, tid = threadIdx.x;
    float y2 = yo[b * 128 + tid] + ff2_b[L * 128 + tid];
#pragma unroll
    for (int ks = 0; ks < 4; ++ks) y2 += part[((size_t)ks * 64 + b) * 128 + tid];
    float m2 = sum128(y2, tid, red) * (1.f / 128.f);
    float c2 = y2 - m2;
    float v2 = sum128(c2 * c2, tid, red) * (1.f / 128.f);
    xs[b * 128 + tid] = c2 * rsqrtf(v2 + 1e-5f) * ln2_g[L * 128 + tid] + ln2_b[L * 128 + tid];
}

// ---------------- mid projection ----------------
__global__ void k_mid(const float* __restrict__ xe, const float* __restrict__ mid_w,
                      const float* __restrict__ mid_b, float* __restrict__ mid) {
    int b = blockIdx.x, c = threadIdx.x;  // 64 threads
    float s = mid_b[c];
    const float* xr = xe + b * 128;
    const float* wr = mid_w + c * 128;
    for (int k = 0; k < 128; ++k) s += xr[k] * wr[k];
    mid[b * 64 + c] = s;
}

// ---------------- conv1: 3->32 direct f32, tile 32x16, COT=16, PX=2 (r13 champion) ----------------
__global__ __launch_bounds__(256, 4) void k_conv1(
    const float* __restrict__ tgt, const float* __restrict__ noise,
    const float* __restrict__ sab, const float* __restrict__ snab,
    const float* __restrict__ wgt, const float* __restrict__ bias,
    unsigned short* __restrict__ h1, int b0) {
    __shared__ float it[3][18][35];
    __shared__ float wt[16][3][9];
    int tid = threadIdx.x;
    int tx = tid & 15, ty = tid >> 4;      // tx: 2-px group, ty: row 0..15
    int total = gridDim.x * gridDim.y * gridDim.z;
    int w = xcd_work(total);
    int bx = w % gridDim.x; int t2 = w / gridDim.x;
    int by = t2 % gridDim.y; int bz = t2 / gridDim.y;
    int bl = bz >> 1, g = bz & 1;
    int bg = b0 + bl, co0 = g * 16;
    float za = sab[bg], zb = snab[bg];
    for (int idx = tid; idx < 3 * 18 * 34; idx += 256) {
        int c = idx / (18 * 34), rem = idx % (18 * 34);
        int yy = rem / 34, xx = rem % 34;
        int gy = by * 16 + yy - 1, gx = bx * 32 + xx - 1;
        float v = 0.f;
        if (gy >= 0 && gy < 128 && gx >= 0 && gx < 128) {
            size_t off = (((size_t)bg * 3 + c) * 128 + gy) * 128 + gx;
            v = za * tgt[off] + zb * noise[off];
        }
        it[c][yy][xx] = v;
    }
    for (int idx = tid; idx < 16 * 27; idx += 256) {
        int co = idx / 27, rem = idx % 27;
        wt[co][rem / 9][rem % 9] = wgt[(size_t)(co0 + co) * 27 + rem];
    }
    __syncthreads();
    float acc[16][2];
#pragma unroll
    for (int co = 0; co < 16; ++co) { acc[co][0] = 0.f; acc[co][1] = 0.f; }
#pragma unroll
    for (int c = 0; c < 3; ++c)
#pragma unroll
        for (int ky = 0; ky < 3; ++ky) {
            float win[4];
#pragma unroll
            for (int i = 0; i < 4; ++i) win[i] = it[c][ty + ky][tx * 2 + i];
#pragma unroll
            for (int kx = 0; kx < 3; ++kx)
#pragma unroll
                for (int co = 0; co < 16; ++co) {
                    float ww = wt[co][c][ky * 3 + kx];
                    acc[co][0] += win[kx] * ww;
                    acc[co][1] += win[kx + 1] * ww;
                }
        }
    int gy = by * 16 + ty, gx0 = bx * 32 + tx * 2;
#pragma unroll
    for (int p = 0; p < 2; ++p) {
        __attribute__((aligned(16))) unsigned short ov[16];
#pragma unroll
        for (int co = 0; co < 16; ++co)
            ov[co] = f2bf(fmaxf(acc[co][p] + bias[co0 + co], 0.f));
        size_t o = (((size_t)bl * 128 + gy) * 128 + gx0 + p) * 32 + co0;
        *(float4*)(h1 + o) = *(float4*)&ov[0];
        *(float4*)(h1 + o + 8) = *(float4*)&ov[8];
    }
}

// ---------------- MFMA 3x3 conv: bf16 NHWC in/out, f32 accum ----------------
template <int CIN, int COB, int COUT, int MOUT>
__global__ __launch_bounds__(256, 2) void k_convMg(
    const unsigned short* __restrict__ in, const unsigned short* __restrict__ wb,
    const float* __restrict__ bias, const float* __restrict__ mid,
    unsigned short* __restrict__ out, int b0) {
    const int GROUPS = COUT / (16 * COB);
    __shared__ __align__(16) unsigned short in_t[10 * 34 * 40];
    __shared__ __align__(16) unsigned short w_t[9 * COB * 16 * 40];
    int tid = threadIdx.x;
    int total = gridDim.x * gridDim.y * gridDim.z;
    int wk = xcd_work(total);
    int bx = wk % gridDim.x; int t2 = wk / gridDim.x;
    int by = t2 % gridDim.y; int bz = t2 / gridDim.y;
    int bl = bz / GROUPS, g = bz % GROUPS;
    int bg = b0 + bl;
    int co0 = g * COB * 16;
    int lane = tid & 63, wv = tid >> 6;
    int l15 = lane & 15, ch = lane >> 4;

    f32x4 acc[2][2][COB];
    f32x4 zf = {0.f, 0.f, 0.f, 0.f};
#pragma unroll
    for (int a = 0; a < 2; ++a)
#pragma unroll
        for (int bq = 0; bq < 2; ++bq)
#pragma unroll
            for (int c = 0; c < COB; ++c) acc[a][bq][c] = zf;

    for (int cs = 0; cs < CIN / 32; ++cs) {
        if (cs) __syncthreads();
        for (int c = tid; c < 10 * 34 * 4; c += 256) {
            int cc = c & 3, pix = c >> 2;
            int xx = pix % 34, yy = pix / 34;
            int gy = by * 8 + yy - 1, gx = bx * 32 + xx - 1;
            bf16x8 v = {0, 0, 0, 0, 0, 0, 0, 0};
            if (gy >= 0 && gy < 128 && gx >= 0 && gx < 128)
                v = *(const bf16x8*)(in + (((size_t)bl * 128 + gy) * 128 + gx) * CIN + cs * 32 + cc * 8);
            *(bf16x8*)(in_t + pix * 40 + cc * 8) = v;
        }
        for (int c = tid; c < 9 * COB * 16 * 4; c += 256) {
            int cc = c & 3, row = c >> 2;
            int tap = row / (COB * 16), co = row % (COB * 16);
            bf16x8 v = *(const bf16x8*)(wb + ((size_t)(tap * COUT + co0 + co)) * CIN + cs * 32 + cc * 8);
            *(bf16x8*)(w_t + row * 40 + cc * 8) = v;
        }
        __syncthreads();
#pragma unroll
        for (int ky = 0; ky < 3; ++ky)
#pragma unroll
            for (int kx = 0; kx < 3; ++kx) {
                int tap = ky * 3 + kx;
                bf16x8 af[COB];
#pragma unroll
                for (int cb = 0; cb < COB; ++cb)
                    af[cb] = *(const bf16x8*)(w_t + (tap * COB * 16 + cb * 16 + l15) * 40 + ch * 8);
#pragma unroll
                for (int yl = 0; yl < 2; ++yl) {
                    int yloc = 2 * wv + yl + ky;
#pragma unroll
                    for (int xt = 0; xt < 2; ++xt) {
                        int xloc = xt * 16 + l15 + kx;
                        bf16x8 bfv = *(const bf16x8*)(in_t + (yloc * 34 + xloc) * 40 + ch * 8);
#pragma unroll
                        for (int cb = 0; cb < COB; ++cb)
                            acc[yl][xt][cb] = __builtin_amdgcn_mfma_f32_16x16x32_bf16(
                                af[cb], bfv, acc[yl][xt][cb], 0, 0, 0);
                    }
                }
            }
    }
#pragma unroll
    for (int yl = 0; yl < 2; ++yl) {
        int gy = by * 8 + 2 * wv + yl;
#pragma unroll
        for (int xt = 0; xt < 2; ++xt) {
            int gx = bx * 32 + xt * 16 + l15;
            size_t pixo = (((size_t)bl * 128 + gy) * 128 + gx) * COUT;
#pragma unroll
            for (int cb = 0; cb < COB; ++cb) {
                int co = co0 + cb * 16 + ch * 4;
                ushort4 o;
#pragma unroll
                for (int r = 0; r < 4; ++r) {
                    float v = acc[yl][xt][cb][r] + bias[co + r];
                    v = fmaxf(v, 0.f);
                    if (MOUT == 2) v += mid[bg * 64 + co + r];
                    ((unsigned short*)&o)[r] = f2bf(v);
                }
                *(ushort4*)(out + pixo + co) = o;
            }
        }
    }
}

// ---------------- u2 via MFMA (co 0..2 of 16-pad) + fused MSE ----------------
__global__ __launch_bounds__(256, 3) void k_u2m(
    const unsigned short* __restrict__ h3, const unsigned short* __restrict__ wbu2,
    const float* __restrict__ u2_b, const float* __restrict__ noise,
    float* __restrict__ partial, int b0) {
    __shared__ __align__(16) unsigned short in_t[340 * 40];
    __shared__ __align__(16) unsigned short w_t[9 * 16 * 40];
    __shared__ float rs[256];
    int tid = threadIdx.x;
    int total = gridDim.x * gridDim.y * gridDim.z;
    int wk = xcd_work(total);
    int bx = wk % gridDim.x; int t2 = wk / gridDim.x;
    int by = t2 % gridDim.y; int bl = t2 / gridDim.y;
    int bg = b0 + bl;
    int lane = tid & 63, wv = tid >> 6, l15 = lane & 15, ch = lane >> 4;

    for (int c = tid; c < 340 * 4; c += 256) {
        int cc = c & 3, pix = c >> 2;
        int xx = pix % 34, yy = pix / 34;
        int gy = by * 8 + yy - 1, gx = bx * 32 + xx - 1;
        bf16x8 v = {0, 0, 0, 0, 0, 0, 0, 0};
        if (gy >= 0 && gy < 128 && gx >= 0 && gx < 128)
            v = *(const bf16x8*)(h3 + (((size_t)bl * 128 + gy) * 128 + gx) * 32 + cc * 8);
        *(bf16x8*)(in_t + pix * 40 + cc * 8) = v;
    }
    for (int c = tid; c < 9 * 16 * 4; c += 256) {
        int cc = c & 3, row = c >> 2;
        bf16x8 v = *(const bf16x8*)(wbu2 + (size_t)row * 32 + cc * 8);
        *(bf16x8*)(w_t + row * 40 + cc * 8) = v;
    }
    __syncthreads();

    f32x4 acc[2][2];
    f32x4 zf = {0.f, 0.f, 0.f, 0.f};
    acc[0][0] = zf; acc[0][1] = zf; acc[1][0] = zf; acc[1][1] = zf;
#pragma unroll
    for (int ky = 0; ky < 3; ++ky)
#pragma unroll
        for (int kx = 0; kx < 3; ++kx) {
            int tap = ky * 3 + kx;
            bf16x8 af = *(const bf16x8*)(w_t + (tap * 16 + l15) * 40 + ch * 8);
#pragma unroll
            for (int yl = 0; yl < 2; ++yl) {
                int yloc = 2 * wv + yl + ky;
#pragma unroll
                for (int xt = 0; xt < 2; ++xt) {
                    int xloc = xt * 16 + l15 + kx;
                    bf16x8 bfv = *(const bf16x8*)(in_t + (yloc * 34 + xloc) * 40 + ch * 8);
                    acc[yl][xt] = __builtin_amdgcn_mfma_f32_16x16x32_bf16(af, bfv, acc[yl][xt], 0, 0, 0);
                }
            }
        }
    float ss = 0.f;
    if (ch == 0) {
#pragma unroll
        for (int yl = 0; yl < 2; ++yl) {
            int gy = by * 8 + 2 * wv + yl;
#pragma unroll
            for (int xt = 0; xt < 2; ++xt) {
                int gx = bx * 32 + xt * 16 + l15;
#pragma unroll
                for (int r = 0; r < 3; ++r) {
                    float v = acc[yl][xt][r] + u2_b[r];
                    float d = v - noise[(((size_t)bg * 3 + r) * 128 + gy) * 128 + gx];
                    ss += d * d;
                }
            }
        }
    }
    rs[tid] = ss;
    __syncthreads();
    for (int s = 128; s > 0; s >>= 1) {
        if (tid < s) rs[tid] += rs[tid + s];
        __syncthreads();
    }
    if (tid == 0) partial[bg * 64 + by * 4 + bx] = rs[0];
}

// ---------------- final MSE reduction ----------------
__global__ void k_final(const float* __restrict__ partial, float* __restrict__ out) {
    __shared__ float rs[256];
    int tid = threadIdx.x;
    float s = 0.f;
    for (int i = tid; i < 4096; i += 256) s += partial[i];
    rs[tid] = s;
    __syncthreads();
    for (int st = 128; st > 0; st >>= 1) {
        if (tid < st) rs[tid] += rs[tid + st];
        __syncthreads();
    }
    if (tid == 0) out[0] = rs[0] / 3145728.0f;
}

extern "C" void kernel_launch(void* const* d_in, const int* in_sizes, int n_in,
                              void* d_out, int out_size, void* d_ws, size_t ws_size,
                              hipStream_t stream) {
    const float* cond   = (const float*)d_in[0];
    const float* tgt    = (const float*)d_in[1];
    const float* noise  = (const float*)d_in[2];
    const int*   t      = (const int*)d_in[3];
    const float* enc_w  = (const float*)d_in[4];
    const float* enc_b  = (const float*)d_in[5];
    const float* in_w   = (const float*)d_in[6];
    const float* in_b   = (const float*)d_in[7];
    const float* out_w  = (const float*)d_in[8];
    const float* out_b  = (const float*)d_in[9];
    const float* ff1_w  = (const float*)d_in[10];
    const float* ff1_b  = (const float*)d_in[11];
    const float* ff2_w  = (const float*)d_in[12];
    const float* ff2_b  = (const float*)d_in[13];
    const float* ln1_g  = (const float*)d_in[14];
    const float* ln1_b  = (const float*)d_in[15];
    const float* ln2_g  = (const float*)d_in[16];
    const float* ln2_b  = (const float*)d_in[17];
    const float* d1_w   = (const float*)d_in[18];
    const float* d1_b   = (const float*)d_in[19];
    const float* d2_w   = (const float*)d_in[20];
    const float* d2_b   = (const float*)d_in[21];
    const float* mid_w  = (const float*)d_in[22];
    const float* mid_b  = (const float*)d_in[23];
    const float* u1_w   = (const float*)d_in[24];
    const float* u1_b   = (const float*)d_in[25];
    const float* u2_w   = (const float*)d_in[26];
    const float* u2_b   = (const float*)d_in[27];

    float* ws = (float*)d_ws;
    // control region: 131072 floats
    float* sab     = ws;                    // 64
    float* snab    = ws + 64;               // 64
    float* x0      = ws + 128;              // 8192
    float* mid     = ws + 16512;            // 4096
    float* msepart = ws + 86144;            // 4096
    unsigned short* wb2  = (unsigned short*)(ws + 90240);   // 18432 bf16
    unsigned short* wbu1 = (unsigned short*)(ws + 99456);   // 18432 bf16
    unsigned short* wbu2 = (unsigned short*)(ws + 108672);  // 4608 bf16

    const size_t SMALL = 131072;
    const size_t ENCP = (size_t)KSEG * 8192;                // 524288
    float* encpart = ws + SMALL;
    float* tfy     = encpart + ENCP;                        // 8192
    unsigned short* tff1 = (unsigned short*)(tfy + 8192);   // 64*2056 bf16 = 65792 f32
    float* tfpart  = tfy + 8192 + 65792;                    // 4*64*128 = 32768
    unsigned short* wbf1 = (unsigned short*)(tfpart + 32768);          // 524288 bf16
    unsigned short* wbf2 = (unsigned short*)(tfpart + 32768 + 262144); // 524288 bf16

    size_t fixed = SMALL + ENCP + 8192 + 65792 + 32768 + 262144 + 262144;
    size_t avail = (ws_size / 4 > fixed) ? (ws_size / 4 - fixed) : 0;
    // per image: h1(32ch) + h2(64ch) + h3(32ch) bf16 = 1048576 f32-slots
    int NB = 1;
    const int cands[7] = {64, 32, 16, 8, 4, 2, 1};
    for (int ci = 0; ci < 7; ++ci) {
        if ((size_t)cands[ci] * 1048576ull <= avail) { NB = cands[ci]; break; }
    }
    unsigned short* hb1 = (unsigned short*)(ws + fixed);
    unsigned short* hb2 = (unsigned short*)(ws + fixed + (size_t)NB * 262144ull);
    unsigned short* hb3 = (unsigned short*)(ws + fixed + (size_t)NB * 786432ull);

    k_alpha<<<1, 64, 0, stream>>>(t, sab, snab);
    k_prep_cw<<<72, 256, 0, stream>>>(d2_w, wb2, 64, 32);
    k_prep_cw<<<72, 256, 0, stream>>>(u1_w, wbu1, 32, 64);
    k_prep_u2<<<18, 256, 0, stream>>>(u2_w, wbu2);
    k_prep_bf<<<2048, 256, 0, stream>>>(ff1_w, wbf1, 524288);
    k_prep_bf<<<2048, 256, 0, stream>>>(ff2_w, wbf2, 524288);
    k_enc_gemm<<<dim3(4, 2, KSEG), 256, 0, stream>>>(cond, enc_w, encpart);
    k_enc_reduce<<<32, 256, 0, stream>>>(encpart, enc_b, x0);
    for (int L = 0; L < 2; ++L) {
        k_tf_attn<<<64, 512, 0, stream>>>(x0, tfy, in_w, in_b, out_w, out_b, ln1_g, ln1_b, L);
        k_ff1m<<<32, 256, 0, stream>>>(tfy, wbf1, ff1_b, tff1, L);
        k_ff2m<<<dim3(4, 2), 256, 0, stream>>>(tff1, wbf2, tfpart, L);
        k_tf_red<<<64, 128, 0, stream>>>(tfpart, tfy, x0, ff2_b, ln2_g, ln2_b, L);
    }
    k_mid<<<64, 64, 0, stream>>>(x0, mid_w, mid_b, mid);

    for (int cb = 0; cb < 64; cb += NB) {
        // conv1: 3->32 direct f32, q_sample fused, 32x16 tiles, 2 groups
        k_conv1<<<dim3(4, 8, NB * 2), 256, 0, stream>>>(
            tgt, noise, sab, snab, d1_w, d1_b, hb1, cb);
        // conv2: 32->64 MFMA, all 64 co per block, relu + mid
        k_convMg<32, 4, 64, 2><<<dim3(4, 16, NB), 256, 0, stream>>>(
            hb1, wb2, d2_b, mid, hb2, cb);
        // u1: 64->32 MFMA, relu
        k_convMg<64, 2, 32, 1><<<dim3(4, 16, NB), 256, 0, stream>>>(
            hb2, wbu1, u1_b, nullptr, hb3, cb);
        // u2: 32->3 MFMA + fused MSE
        k_u2m<<<dim3(4, 16, NB), 256, 0, stream>>>(
            hb3, wbu2, u2_b, noise, msepart, cb);
    }

    k_final<<<1, 256, 0, stream>>>(msepart, (float*)d_out);
}